// Round 14
// baseline (225.416 us; speedup 1.0000x reference)
//
#include <hip/hip_runtime.h>
#include <hip/hip_bf16.h>

#define FS 24
#define NPATCH 576
#define EMBD 768
#define KDIM 768
#define NB 64
#define IMGW 384
#define MTOT (NB*NPATCH)       // 36864
#define EPSV 1e-4f

#define O2_OFS (MTOT*EMBD)     // 28311552
#define G1_OFS (2*O2_OFS)      // 56623104
#define G2_OFS (G1_OFS + NB*4)

// workspace float-region layout (float indices at byte offset 0)
#define WS_G1 0
#define WS_G2 256
#define WS_SK1 512
#define WS_SK2 576
#define WS_MEAN1 1024
#define WS_STD1 (WS_MEAN1 + NB*EMBD)
#define WS_MEAN2 (WS_STD1 + NB*EMBD)
#define WS_STD2 (WS_MEAN2 + NB*EMBD)

// bf16 W (linear [n][k]) at byte offset 1 MiB in ws
#define WSB_W  1048576ULL
#define WS_NEED (WSB_W + 1179648ULL)   // 2,228,224 B (proven available)

typedef __attribute__((ext_vector_type(8))) short bf16x8;
typedef __attribute__((ext_vector_type(4))) unsigned short u16x4;
typedef __attribute__((ext_vector_type(8))) unsigned short u16x8;
typedef __attribute__((ext_vector_type(4))) float f32x4;

__device__ __forceinline__ u16x4 cvt4_bf16(f32x4 v) {
    u16x4 r;
#pragma unroll
    for (int j = 0; j < 4; ++j) r[j] = __builtin_bit_cast(unsigned short, (__bf16)v[j]);
    return r;
}

__device__ __forceinline__ u16x8 cvt8u_bf16(f32x4 lo, f32x4 hi) {
    u16x4 a = cvt4_bf16(lo), b = cvt4_bf16(hi);
    u16x8 v;
#pragma unroll
    for (int q = 0; q < 4; ++q) { v[q] = a[q]; v[q+4] = b[q]; }
    return v;
}

__device__ __forceinline__ void gload16(const void* g, const void* l) {
    __builtin_amdgcn_global_load_lds(
        (const __attribute__((address_space(1))) unsigned int*)g,
        (__attribute__((address_space(3))) unsigned int*)l, 16, 0, 0);
}

// ---------------- boxes (exact f32 port) ------------------------------------
__device__ inline float occ_of(const float b1[4], const float b2[4]) {
    float ixmin = fmaxf(b1[0], b2[0]);
    float iymin = fmaxf(b1[1], b2[1]);
    float ixmax = fminf(b1[2], b2[2]);
    float iymax = fminf(b1[3], b2[3]);
    float iv = fmaxf(iymax - iymin, 0.f) * fmaxf(ixmax - ixmin, 0.f);
    float v1 = (b1[2] - b1[0]) * (b1[3] - b1[1]);
    return (iv + 1e-8f) / (v1 + 1e-8f);
}

__device__ inline void upd_box(const float* b1, const float* b2, float* o) {
    float x0 = b1[0], y0 = b1[1], x2 = b1[2], y2 = b1[3];
    float q0 = b2[0], q1 = b2[1], q2 = b2[2], q3 = b2[3];
    bool condA = (x0 >= q0) && (x2 <= q2);
    bool subA1 = (q1 <= y0) && (q3 > y0);
    bool a1 = condA && subA1;
    bool a2 = condA && !subA1 && (q3 >= y2) && (q1 < y2);
    bool condB = !condA && (y0 >= q1) && (y2 <= q3);
    bool subB1 = (q0 <= x0) && (q2 > x0);
    bool bb1 = condB && subB1;
    bool bb2 = condB && !subB1 && (q2 >= x2) && (q0 < x2);
    o[1] = a1 ? q3 : y0;
    o[3] = a2 ? q1 : y2;
    o[0] = bb1 ? q2 : x0;
    o[2] = bb2 ? q0 : x2;
}

__global__ void boxes_kernel(const float* __restrict__ gt1, const float* __restrict__ gt2,
                             float* __restrict__ gout1, float* __restrict__ gout2,
                             float* __restrict__ ws) {
    const int b = threadIdx.x;
    if (b >= NB) return;
    float g1[4], g2[4];
    {
        float p0 = gt1[b*4+0]*(float)IMGW, p1 = gt1[b*4+1]*(float)IMGW;
        float p2 = gt1[b*4+2]*(float)IMGW, p3 = gt1[b*4+3]*(float)IMGW;
        g1[0] = rintf(p0 / 16.f);
        g1[1] = rintf(p1 / 16.f);
        g1[2] = rintf((p0 + p2 - 1.f) / 16.f);
        g1[3] = rintf((p1 + p3 - 1.f) / 16.f);
    }
    {
        float p0 = gt2[b*4+0]*(float)IMGW, p1 = gt2[b*4+1]*(float)IMGW;
        float p2 = gt2[b*4+2]*(float)IMGW, p3 = gt2[b*4+3]*(float)IMGW;
        g2[0] = rintf(p0 / 16.f);
        g2[1] = rintf(p1 / 16.f);
        g2[2] = rintf((p0 + p2 - 1.f) / 16.f);
        g2[3] = rintf((p1 + p3 - 1.f) / 16.f);
    }
    float occ1 = occ_of(g1, g2), occ2 = occ_of(g2, g1);
    const float fsf = (float)FS;
    bool skip1 = (occ1 > 0.5f) || (g2[3] <= g2[1]) || (g2[2] <= g2[0]) ||
                 (g2[0] < 0.f) || (g2[1] < 0.f) || (g2[0] >= fsf) || (g2[1] >= fsf);
    bool skip2 = (occ2 > 0.5f) || (g1[3] <= g1[1]) || (g1[2] <= g1[0]) ||
                 (g1[0] < 0.f) || (g1[1] < 0.f) || (g1[0] >= fsf) || (g1[1] >= fsf);

    float n1[4], n2[4];
    upd_box(g1, g2, n1);
    upd_box(g2, g1, n2);
    if (skip1) { n1[0]=g1[0]; n1[1]=g1[1]; n1[2]=g1[2]; n1[3]=g1[3]; }
    if (skip2) { n2[0]=g2[0]; n2[1]=g2[1]; n2[2]=g2[2]; n2[3]=g2[3]; }

    gout1[b*4+0] = n1[0]; gout1[b*4+1] = n1[1];
    gout1[b*4+2] = n1[2] - n1[0]; gout1[b*4+3] = n1[3] - n1[1];
    gout2[b*4+0] = n2[0]; gout2[b*4+1] = n2[1];
    gout2[b*4+2] = n2[2] - n2[0]; gout2[b*4+3] = n2[3] - n2[1];

#pragma unroll
    for (int i = 0; i < 4; ++i) { ws[WS_G1 + b*4 + i] = g1[i]; ws[WS_G2 + b*4 + i] = g2[i]; }
    ws[WS_SK1 + b] = skip1 ? 1.f : 0.f;
    ws[WS_SK2 + b] = skip2 ? 1.f : 0.f;
}

// ---- pre-convert W f32 -> bf16, LINEAR [n][k] ------------------------------
__global__ void cvt_w_kernel(const float* __restrict__ Wm, unsigned short* __restrict__ Wb) {
    const int idx = blockIdx.x * 256 + threadIdx.x;   // 73728 chunks of 8
    const f32x4 a = *reinterpret_cast<const f32x4*>(Wm + idx*8);
    const f32x4 b = *reinterpret_cast<const f32x4*>(Wm + idx*8 + 4);
    *reinterpret_cast<u16x8*>(Wb + idx*8) = cvt8u_bf16(a, b);
}

// ---- fused-im2col GEMM (r12 champion, verbatim): BM=128, BN=256, BK=64,
// A bf16 reg-staged, B via global_load_lds, 2 blocks/CU, 240 joint regs.
__global__ __launch_bounds__(256, 2)
void gemm_abf16_kernel(const float* __restrict__ x1, const float* __restrict__ xx2,
                       const unsigned short* __restrict__ Wb,
                       const float* __restrict__ bias,
                       float* __restrict__ out) {
    __shared__ __align__(16) unsigned char ldsA[16384];   // bf16 [128][64]
    __shared__ __align__(16) unsigned char ldsB[32768];   // bf16 [256][64]

    const float* __restrict__ xin = blockIdx.y ? xx2 : x1;
    float* __restrict__ oo = out + (size_t)blockIdx.y * (size_t)O2_OFS;

    const int bx = blockIdx.x;                 // 864 = 8 * 108
    const int swz = (bx & 7) * 108 + (bx >> 3);
    const int mt = swz / 3;
    const int nt = swz - mt * 3;
    const int m0 = mt * 128;
    const int n0 = nt * 256;

    const int tid = threadIdx.x;

    int aoffA[4];
#pragma unroll
    for (int j = 0; j < 4; ++j) {
        const int ci = tid + 256*j;
        const int row = ci >> 3, c8 = ci & 7;
        const int m = m0 + row;
        const int bb = m / NPATCH;
        const int p  = m - bb*NPATCH;
        const int py = p / FS, px = p - py*FS;
        aoffA[j] = ((bb*3)*IMGW + py*16 + (c8 >> 1)) * IMGW + px*16 + (c8 & 1)*8;
    }
    const int lofsA0 = (tid*16) ^ (((tid >> 3) & 7) << 4);
    int boff0;
    {
        const int row = tid >> 3, pos = tid & 7;
        boff0 = (n0 + row)*KDIM + ((pos ^ (row & 7)) << 3);
    }
    const int ldsuni = (tid & 192) * 16;

    f32x4 acc[4][8];
#pragma unroll
    for (int i = 0; i < 4; ++i)
#pragma unroll
        for (int j = 0; j < 8; ++j) acc[i][j] = (f32x4){0.f, 0.f, 0.f, 0.f};

    const int l  = tid & 63;
    const int wid = tid >> 6;
    const int wr = wid >> 1, wc = wid & 1;
    const int fr = l & 15, fq = l >> 4;

    f32x4 LA[4][2];

#pragma unroll
    for (int j = 0; j < 4; ++j) {
        LA[j][0] = *reinterpret_cast<const f32x4*>(xin + aoffA[j]);
        LA[j][1] = *reinterpret_cast<const f32x4*>(xin + aoffA[j] + 4);
    }

    for (int kt = 0; kt < 12; ++kt) {
        asm volatile("s_barrier" ::: "memory");
#pragma unroll
        for (int j = 0; j < 8; ++j)
            gload16(Wb + boff0 + j*24576 + kt*64, ldsB + ldsuni + j*4096);
        __builtin_amdgcn_sched_barrier(0);
#pragma unroll
        for (int j = 0; j < 4; ++j)
            *reinterpret_cast<u16x8*>(ldsA + lofsA0 + j*4096)
                = cvt8u_bf16(LA[j][0], LA[j][1]);
        __builtin_amdgcn_sched_barrier(0);
        if (kt + 1 < 12) {
            const int dA = ((kt+1) >> 2)*(IMGW*IMGW) + ((kt+1) & 3)*(4*IMGW);
#pragma unroll
            for (int j = 0; j < 4; ++j) {
                LA[j][0] = *reinterpret_cast<const f32x4*>(xin + aoffA[j] + dA);
                LA[j][1] = *reinterpret_cast<const f32x4*>(xin + aoffA[j] + dA + 4);
            }
            asm volatile("s_waitcnt vmcnt(8) lgkmcnt(0)\ns_barrier" ::: "memory");
        } else {
            asm volatile("s_waitcnt vmcnt(0) lgkmcnt(0)\ns_barrier" ::: "memory");
        }
        __builtin_amdgcn_sched_barrier(0);

#pragma unroll
        for (int ko = 0; ko < 2; ++ko) {
            const int colb = ko*64 + fq*16;
            bf16x8 af[4];
#pragma unroll
            for (int mi = 0; mi < 4; ++mi) {
                const int r = wr*64 + mi*16 + fr;
                af[mi] = *reinterpret_cast<const bf16x8*>(
                    ldsA + r*128 + (colb ^ ((r & 7) << 4)));
            }
#pragma unroll
            for (int nq = 0; nq < 2; ++nq) {
                bf16x8 bfv[4];
#pragma unroll
                for (int nj = 0; nj < 4; ++nj) {
                    const int rn = wc*128 + nq*64 + nj*16 + fr;
                    bfv[nj] = *reinterpret_cast<const bf16x8*>(
                        ldsB + rn*128 + (((ko*4 + fq) ^ (rn & 7)) << 4));
                }
                __builtin_amdgcn_s_setprio(1);
#pragma unroll
                for (int mi = 0; mi < 4; ++mi)
#pragma unroll
                    for (int nj = 0; nj < 4; ++nj)
                        acc[mi][nq*4 + nj] = __builtin_amdgcn_mfma_f32_16x16x32_bf16(
                            af[mi], bfv[nj], acc[mi][nq*4 + nj], 0, 0, 0);
                __builtin_amdgcn_s_setprio(0);
            }
        }
    }

#pragma unroll
    for (int ni = 0; ni < 8; ++ni) {
        const int col = n0 + wc*128 + ni*16 + fr;
        const float bv = bias[col];
#pragma unroll
        for (int mi = 0; mi < 4; ++mi) {
            const int rowb = m0 + wr*64 + mi*16 + fq*4;
#pragma unroll
            for (int r = 0; r < 4; ++r)
                oo[(size_t)(rowb + r)*EMBD + col] = acc[mi][ni][r] + bv;
        }
    }
}

// ---------------- FALLBACK GEMM (round-0, known-good) -----------------------
__global__ __launch_bounds__(256, 2)
void embed_gemm_kernel(const float* __restrict__ x1, const float* __restrict__ xx2,
                       const float* __restrict__ Wm, const float* __restrict__ bias,
                       float* __restrict__ out) {
    __shared__ __align__(16) unsigned char As[128*64*2];
    __shared__ __align__(16) unsigned char Bs[128*64*2];

    const float* __restrict__ xin = blockIdx.y ? xx2 : x1;
    float* __restrict__ oo = out + (size_t)blockIdx.y * (size_t)O2_OFS;

    const int bx = blockIdx.x;
    const int swz = (bx & 7) * (1728/8) + (bx >> 3);
    const int mt = swz / 6;
    const int nt = swz - mt * 6;
    const int m0 = mt * 128;
    const int n0 = nt * 128;

    const int tid = threadIdx.x;

    int boffA[8], boffB[8], lofs[8];
#pragma unroll
    for (int it = 0; it < 8; ++it) {
        const int ci = tid + 256*it;
        const int row = ci >> 4, col4 = ci & 15;
        const int m = m0 + row;
        const int bb = m / NPATCH;
        const int p  = m - bb*NPATCH;
        const int py = p / FS, px = p - py*FS;
        boffA[it] = ((bb*3)*IMGW + py*16 + (col4 >> 2)) * IMGW + px*16 + (col4 & 3)*4;
        boffB[it] = (n0 + row)*KDIM + col4*4;
        lofs[it]  = (ci*8) ^ ((row & 7) << 4);
    }

    f32x4 acc[4][4];
#pragma unroll
    for (int i = 0; i < 4; ++i)
#pragma unroll
        for (int j = 0; j < 4; ++j) acc[i][j] = (f32x4){0.f, 0.f, 0.f, 0.f};

    f32x4 stA[8], stB[8];
#pragma unroll
    for (int it = 0; it < 8; ++it) {
        stA[it] = *reinterpret_cast<const f32x4*>(xin + boffA[it]);
        stB[it] = *reinterpret_cast<const f32x4*>(Wm + boffB[it]);
    }

    const int l  = tid & 63;
    const int wid = tid >> 6;
    const int wr = wid >> 1, wc = wid & 1;
    const int fr = l & 15, fq = l >> 4;
    const int xorv = (fr & 7) << 4;

    for (int kt = 0; kt < 12; ++kt) {
        __syncthreads();
#pragma unroll
        for (int it = 0; it < 8; ++it) {
            *reinterpret_cast<u16x4*>(As + lofs[it]) = cvt4_bf16(stA[it]);
            *reinterpret_cast<u16x4*>(Bs + lofs[it]) = cvt4_bf16(stB[it]);
        }
        if (kt + 1 < 12) {
            const int dA = ((kt+1) >> 2) * (IMGW*IMGW) + ((kt+1) & 3) * (4*IMGW);
            const int dB = (kt+1) * 64;
#pragma unroll
            for (int it = 0; it < 8; ++it) {
                stA[it] = *reinterpret_cast<const f32x4*>(xin + boffA[it] + dA);
                stB[it] = *reinterpret_cast<const f32x4*>(Wm + boffB[it] + dB);
            }
        }
        __syncthreads();
#pragma unroll
        for (int ko = 0; ko < 2; ++ko) {
            const int colb = ko*64 + fq*16;
            bf16x8 af[4], bf4[4];
#pragma unroll
            for (int i = 0; i < 4; ++i) {
                af[i]  = *reinterpret_cast<const bf16x8*>(As + (wr*64 + i*16 + fr)*128 + (colb ^ xorv));
                bf4[i] = *reinterpret_cast<const bf16x8*>(Bs + (wc*64 + i*16 + fr)*128 + (colb ^ xorv));
            }
#pragma unroll
            for (int mi = 0; mi < 4; ++mi)
#pragma unroll
                for (int ni = 0; ni < 4; ++ni)
                    acc[mi][ni] = __builtin_amdgcn_mfma_f32_16x16x32_bf16(
                        af[mi], bf4[ni], acc[mi][ni], 0, 0, 0);
        }
    }

#pragma unroll
    for (int ni = 0; ni < 4; ++ni) {
        const int col = n0 + wc*64 + ni*16 + fr;
        const float bv = bias[col];
#pragma unroll
        for (int mi = 0; mi < 4; ++mi) {
            const int rowb = m0 + wr*64 + mi*16 + fq*4;
#pragma unroll
            for (int r = 0; r < 4; ++r)
                oo[(size_t)(rowb + r)*EMBD + col] = acc[mi][ni][r] + bv;
        }
    }
}

// ---------------- masked per-channel stats ----------------------------------
__global__ void stats_kernel(const float* __restrict__ o1, const float* __restrict__ o2,
                             float* __restrict__ ws) {
    const int b = blockIdx.y;
    const int c = blockIdx.x * 256 + threadIdx.x;

    float g1[4], g2[4];
#pragma unroll
    for (int i = 0; i < 4; ++i) { g1[i] = ws[WS_G1 + b*4 + i]; g2[i] = ws[WS_G2 + b*4 + i]; }

    for (int t = 0; t < 2; ++t) {
        const float* f = t ? o2 : o1;
        const float* g = t ? g2 : g1;
        int xlo = max(0, (int)g[0]);
        int xhi = min(FS, (int)g[2]);
        int ylo = max(0, (int)g[1]);
        int yhi = min(FS, (int)g[3]);
        float s = 0.f, ss = 0.f;
        for (int py = ylo; py < yhi; ++py)
            for (int px = xlo; px < xhi; ++px) {
                float v = f[(size_t)(b*NPATCH + py*FS + px)*EMBD + c];
                s += v; ss += v*v;
            }
        int nx = xhi - xlo; if (nx < 0) nx = 0;
        int ny = yhi - ylo; if (ny < 0) ny = 0;
        float n = (float)(nx*ny);
        float mean = s / fmaxf(n, 1.f);
        float var = (ss - 2.f*mean*s + n*mean*mean) / fmaxf(n - 1.f, 1.f);
        float sd = sqrtf(fmaxf(var, 0.f));
        ws[(t ? WS_MEAN2 : WS_MEAN1) + b*EMBD + c] = mean;
        ws[(t ? WS_STD2 : WS_STD1) + b*EMBD + c] = sd;
    }
}

// ---------------- blend: COMPACT grid (9 x NB), 64 patches/block ------------
// Same math/order as the proven mega-grid version (read f1,f2 before any
// write, per patch, per thread). Patch ranges disjoint across blocks; full
// channel dim within a block -> race-free. Stats/box loads hoisted.
__global__ void blend_kernel(float* __restrict__ o1, float* __restrict__ o2,
                             const float* __restrict__ ws) {
    const int b = blockIdx.y;

    const float sk1 = ws[WS_SK1 + b];
    const float sk2 = ws[WS_SK2 + b];
    const bool any1 = (sk1 == 0.f);
    const bool any2 = (sk2 == 0.f);
    if (!any1 && !any2) return;

    float G1[4], G2[4];
#pragma unroll
    for (int i = 0; i < 4; ++i) { G1[i] = ws[WS_G1 + b*4 + i]; G2[i] = ws[WS_G2 + b*4 + i]; }

    const int c = threadIdx.x * 4;
    const f32x4 m1 = *reinterpret_cast<const f32x4*>(ws + WS_MEAN1 + b*EMBD + c);
    const f32x4 s1 = *reinterpret_cast<const f32x4*>(ws + WS_STD1  + b*EMBD + c);
    const f32x4 m2 = *reinterpret_cast<const f32x4*>(ws + WS_MEAN2 + b*EMBD + c);
    const f32x4 s2 = *reinterpret_cast<const f32x4*>(ws + WS_STD2  + b*EMBD + c);

    const int p0 = blockIdx.x * 64;
    for (int p = p0; p < p0 + 64; ++p) {
        const int py = p / FS, px = p - py*FS;
        const float pxf = (float)px, pyf = (float)py;
        const bool in1 = (pxf >= G1[0]) && (pxf < G1[2]) && (pyf >= G1[1]) && (pyf < G1[3]);
        const bool in2 = (pxf >= G2[0]) && (pxf < G2[2]) && (pyf >= G2[1]) && (pyf < G2[3]);
        const bool do1 = any1 && in2;   // out1 blended over mask m2
        const bool do2 = any2 && in1;   // out2 blended over mask m1
        if (!do1 && !do2) continue;

        const size_t base = (size_t)(b*NPATCH + p)*EMBD + c;
        const f32x4 f1 = *reinterpret_cast<const f32x4*>(o1 + base);
        const f32x4 f2 = *reinterpret_cast<const f32x4*>(o2 + base);

        if (do1) {
            f32x4 r;
#pragma unroll
            for (int j = 0; j < 4; ++j)
                r[j] = (f2[j] - m2[j]) / (s2[j] + EPSV) * (s1[j] + EPSV) + m1[j];
            *reinterpret_cast<f32x4*>(o1 + base) = r;
        }
        if (do2) {
            f32x4 r;
#pragma unroll
            for (int j = 0; j < 4; ++j)
                r[j] = (f1[j] - m1[j]) / (s1[j] + EPSV) * (s2[j] + EPSV) + m2[j];
            *reinterpret_cast<f32x4*>(o2 + base) = r;
        }
    }
}

extern "C" void kernel_launch(void* const* d_in, const int* in_sizes, int n_in,
                              void* d_out, int out_size, void* d_ws, size_t ws_size,
                              hipStream_t stream) {
    const float* x    = (const float*)d_in[0];
    const float* x2   = (const float*)d_in[1];
    const float* gt1  = (const float*)d_in[2];
    const float* gt2  = (const float*)d_in[3];
    const float* Wm   = (const float*)d_in[4];
    const float* bias = (const float*)d_in[5];
    float* out = (float*)d_out;
    float* ws  = (float*)d_ws;

    float* o1 = out;
    float* o2 = out + O2_OFS;
    float* g1n = out + G1_OFS;
    float* g2n = out + G2_OFS;

    boxes_kernel<<<1, 64, 0, stream>>>(gt1, gt2, g1n, g2n, ws);

    if (ws_size >= WS_NEED) {
        unsigned short* Wb = (unsigned short*)((char*)d_ws + WSB_W);
        cvt_w_kernel<<<288, 256, 0, stream>>>(Wm, Wb);
        gemm_abf16_kernel<<<dim3(864, 2), 256, 0, stream>>>(x, x2, Wb, bias, out);
    } else {
        embed_gemm_kernel<<<dim3(1728, 2), 256, 0, stream>>>(x, x2, Wm, bias, out);
    }

    stats_kernel<<<dim3(3, NB), 256, 0, stream>>>(o1, o2, ws);
    blend_kernel<<<dim3(9, NB), 192, 0, stream>>>(o1, o2, ws);
}

// Round 15
// 188.912 us; speedup vs baseline: 1.1932x; 1.1932x over previous
//
#include <hip/hip_runtime.h>
#include <hip/hip_bf16.h>

#define FS 24
#define NPATCH 576
#define EMBD 768
#define KDIM 768
#define NB 64
#define IMGW 384
#define MTOT (NB*NPATCH)       // 36864
#define EPSV 1e-4f

#define O2_OFS (MTOT*EMBD)     // 28311552
#define G1_OFS (2*O2_OFS)      // 56623104
#define G2_OFS (G1_OFS + NB*4)

// workspace float-region layout (float indices at byte offset 0)
#define WS_G1 0
#define WS_G2 256
#define WS_SK1 512
#define WS_SK2 576
#define WS_MEAN1 1024
#define WS_STD1 (WS_MEAN1 + NB*EMBD)
#define WS_MEAN2 (WS_STD1 + NB*EMBD)
#define WS_STD2 (WS_MEAN2 + NB*EMBD)

// bf16 W (linear [n][k]) at byte offset 1 MiB in ws
#define WSB_W  1048576ULL
#define WS_NEED (WSB_W + 1179648ULL)   // 2,228,224 B (proven available)

typedef __attribute__((ext_vector_type(8))) short bf16x8;
typedef __attribute__((ext_vector_type(4))) unsigned short u16x4;
typedef __attribute__((ext_vector_type(8))) unsigned short u16x8;
typedef __attribute__((ext_vector_type(4))) float f32x4;

__device__ __forceinline__ u16x4 cvt4_bf16(f32x4 v) {
    u16x4 r;
#pragma unroll
    for (int j = 0; j < 4; ++j) r[j] = __builtin_bit_cast(unsigned short, (__bf16)v[j]);
    return r;
}

__device__ __forceinline__ u16x8 cvt8u_bf16(f32x4 lo, f32x4 hi) {
    u16x4 a = cvt4_bf16(lo), b = cvt4_bf16(hi);
    u16x8 v;
#pragma unroll
    for (int q = 0; q < 4; ++q) { v[q] = a[q]; v[q+4] = b[q]; }
    return v;
}

__device__ __forceinline__ void gload16(const void* g, const void* l) {
    __builtin_amdgcn_global_load_lds(
        (const __attribute__((address_space(1))) unsigned int*)g,
        (__attribute__((address_space(3))) unsigned int*)l, 16, 0, 0);
}

// ---------------- boxes helpers (exact f32 port) -----------------------------
__device__ inline float occ_of(const float b1[4], const float b2[4]) {
    float ixmin = fmaxf(b1[0], b2[0]);
    float iymin = fmaxf(b1[1], b2[1]);
    float ixmax = fminf(b1[2], b2[2]);
    float iymax = fminf(b1[3], b2[3]);
    float iv = fmaxf(iymax - iymin, 0.f) * fmaxf(ixmax - ixmin, 0.f);
    float v1 = (b1[2] - b1[0]) * (b1[3] - b1[1]);
    return (iv + 1e-8f) / (v1 + 1e-8f);
}

__device__ inline void upd_box(const float* b1, const float* b2, float* o) {
    float x0 = b1[0], y0 = b1[1], x2 = b1[2], y2 = b1[3];
    float q0 = b2[0], q1 = b2[1], q2 = b2[2], q3 = b2[3];
    bool condA = (x0 >= q0) && (x2 <= q2);
    bool subA1 = (q1 <= y0) && (q3 > y0);
    bool a1 = condA && subA1;
    bool a2 = condA && !subA1 && (q3 >= y2) && (q1 < y2);
    bool condB = !condA && (y0 >= q1) && (y2 <= q3);
    bool subB1 = (q0 <= x0) && (q2 > x0);
    bool bb1 = condB && subB1;
    bool bb2 = condB && !subB1 && (q2 >= x2) && (q0 < x2);
    o[1] = a1 ? q3 : y0;
    o[3] = a2 ? q1 : y2;
    o[0] = bb1 ? q2 : x0;
    o[2] = bb2 ? q0 : x2;
}

// ---- merged init kernel: block 0 = boxes, blocks 1..288 = cvt_w ------------
__global__ void init_kernel(const float* __restrict__ gt1, const float* __restrict__ gt2,
                            float* __restrict__ gout1, float* __restrict__ gout2,
                            float* __restrict__ ws,
                            const float* __restrict__ Wm, unsigned short* __restrict__ Wb) {
    if (blockIdx.x > 0) {
        // cvt_w path (identical math to proven cvt_w_kernel)
        const int idx = (blockIdx.x - 1) * 256 + threadIdx.x;   // 73728 chunks of 8
        const f32x4 a = *reinterpret_cast<const f32x4*>(Wm + idx*8);
        const f32x4 b = *reinterpret_cast<const f32x4*>(Wm + idx*8 + 4);
        *reinterpret_cast<u16x8*>(Wb + idx*8) = cvt8u_bf16(a, b);
        return;
    }
    const int b = threadIdx.x;
    if (b >= NB) return;
    float g1[4], g2[4];
    {
        float p0 = gt1[b*4+0]*(float)IMGW, p1 = gt1[b*4+1]*(float)IMGW;
        float p2 = gt1[b*4+2]*(float)IMGW, p3 = gt1[b*4+3]*(float)IMGW;
        g1[0] = rintf(p0 / 16.f);
        g1[1] = rintf(p1 / 16.f);
        g1[2] = rintf((p0 + p2 - 1.f) / 16.f);
        g1[3] = rintf((p1 + p3 - 1.f) / 16.f);
    }
    {
        float p0 = gt2[b*4+0]*(float)IMGW, p1 = gt2[b*4+1]*(float)IMGW;
        float p2 = gt2[b*4+2]*(float)IMGW, p3 = gt2[b*4+3]*(float)IMGW;
        g2[0] = rintf(p0 / 16.f);
        g2[1] = rintf(p1 / 16.f);
        g2[2] = rintf((p0 + p2 - 1.f) / 16.f);
        g2[3] = rintf((p1 + p3 - 1.f) / 16.f);
    }
    float occ1 = occ_of(g1, g2), occ2 = occ_of(g2, g1);
    const float fsf = (float)FS;
    bool skip1 = (occ1 > 0.5f) || (g2[3] <= g2[1]) || (g2[2] <= g2[0]) ||
                 (g2[0] < 0.f) || (g2[1] < 0.f) || (g2[0] >= fsf) || (g2[1] >= fsf);
    bool skip2 = (occ2 > 0.5f) || (g1[3] <= g1[1]) || (g1[2] <= g1[0]) ||
                 (g1[0] < 0.f) || (g1[1] < 0.f) || (g1[0] >= fsf) || (g1[1] >= fsf);

    float n1[4], n2[4];
    upd_box(g1, g2, n1);
    upd_box(g2, g1, n2);
    if (skip1) { n1[0]=g1[0]; n1[1]=g1[1]; n1[2]=g1[2]; n1[3]=g1[3]; }
    if (skip2) { n2[0]=g2[0]; n2[1]=g2[1]; n2[2]=g2[2]; n2[3]=g2[3]; }

    gout1[b*4+0] = n1[0]; gout1[b*4+1] = n1[1];
    gout1[b*4+2] = n1[2] - n1[0]; gout1[b*4+3] = n1[3] - n1[1];
    gout2[b*4+0] = n2[0]; gout2[b*4+1] = n2[1];
    gout2[b*4+2] = n2[2] - n2[0]; gout2[b*4+3] = n2[3] - n2[1];

#pragma unroll
    for (int i = 0; i < 4; ++i) { ws[WS_G1 + b*4 + i] = g1[i]; ws[WS_G2 + b*4 + i] = g2[i]; }
    ws[WS_SK1 + b] = skip1 ? 1.f : 0.f;
    ws[WS_SK2 + b] = skip2 ? 1.f : 0.f;
}

// ---- fused-im2col GEMM (r12 champion, verbatim): BM=128, BN=256, BK=64,
// A bf16 reg-staged, B via global_load_lds, 2 blocks/CU, 240 joint regs.
__global__ __launch_bounds__(256, 2)
void gemm_abf16_kernel(const float* __restrict__ x1, const float* __restrict__ xx2,
                       const unsigned short* __restrict__ Wb,
                       const float* __restrict__ bias,
                       float* __restrict__ out) {
    __shared__ __align__(16) unsigned char ldsA[16384];   // bf16 [128][64]
    __shared__ __align__(16) unsigned char ldsB[32768];   // bf16 [256][64]

    const float* __restrict__ xin = blockIdx.y ? xx2 : x1;
    float* __restrict__ oo = out + (size_t)blockIdx.y * (size_t)O2_OFS;

    const int bx = blockIdx.x;                 // 864 = 8 * 108
    const int swz = (bx & 7) * 108 + (bx >> 3);
    const int mt = swz / 3;
    const int nt = swz - mt * 3;
    const int m0 = mt * 128;
    const int n0 = nt * 256;

    const int tid = threadIdx.x;

    int aoffA[4];
#pragma unroll
    for (int j = 0; j < 4; ++j) {
        const int ci = tid + 256*j;
        const int row = ci >> 3, c8 = ci & 7;
        const int m = m0 + row;
        const int bb = m / NPATCH;
        const int p  = m - bb*NPATCH;
        const int py = p / FS, px = p - py*FS;
        aoffA[j] = ((bb*3)*IMGW + py*16 + (c8 >> 1)) * IMGW + px*16 + (c8 & 1)*8;
    }
    const int lofsA0 = (tid*16) ^ (((tid >> 3) & 7) << 4);
    int boff0;
    {
        const int row = tid >> 3, pos = tid & 7;
        boff0 = (n0 + row)*KDIM + ((pos ^ (row & 7)) << 3);
    }
    const int ldsuni = (tid & 192) * 16;

    f32x4 acc[4][8];
#pragma unroll
    for (int i = 0; i < 4; ++i)
#pragma unroll
        for (int j = 0; j < 8; ++j) acc[i][j] = (f32x4){0.f, 0.f, 0.f, 0.f};

    const int l  = tid & 63;
    const int wid = tid >> 6;
    const int wr = wid >> 1, wc = wid & 1;
    const int fr = l & 15, fq = l >> 4;

    f32x4 LA[4][2];

#pragma unroll
    for (int j = 0; j < 4; ++j) {
        LA[j][0] = *reinterpret_cast<const f32x4*>(xin + aoffA[j]);
        LA[j][1] = *reinterpret_cast<const f32x4*>(xin + aoffA[j] + 4);
    }

    for (int kt = 0; kt < 12; ++kt) {
        asm volatile("s_barrier" ::: "memory");
#pragma unroll
        for (int j = 0; j < 8; ++j)
            gload16(Wb + boff0 + j*24576 + kt*64, ldsB + ldsuni + j*4096);
        __builtin_amdgcn_sched_barrier(0);
#pragma unroll
        for (int j = 0; j < 4; ++j)
            *reinterpret_cast<u16x8*>(ldsA + lofsA0 + j*4096)
                = cvt8u_bf16(LA[j][0], LA[j][1]);
        __builtin_amdgcn_sched_barrier(0);
        if (kt + 1 < 12) {
            const int dA = ((kt+1) >> 2)*(IMGW*IMGW) + ((kt+1) & 3)*(4*IMGW);
#pragma unroll
            for (int j = 0; j < 4; ++j) {
                LA[j][0] = *reinterpret_cast<const f32x4*>(xin + aoffA[j] + dA);
                LA[j][1] = *reinterpret_cast<const f32x4*>(xin + aoffA[j] + dA + 4);
            }
            asm volatile("s_waitcnt vmcnt(8) lgkmcnt(0)\ns_barrier" ::: "memory");
        } else {
            asm volatile("s_waitcnt vmcnt(0) lgkmcnt(0)\ns_barrier" ::: "memory");
        }
        __builtin_amdgcn_sched_barrier(0);

#pragma unroll
        for (int ko = 0; ko < 2; ++ko) {
            const int colb = ko*64 + fq*16;
            bf16x8 af[4];
#pragma unroll
            for (int mi = 0; mi < 4; ++mi) {
                const int r = wr*64 + mi*16 + fr;
                af[mi] = *reinterpret_cast<const bf16x8*>(
                    ldsA + r*128 + (colb ^ ((r & 7) << 4)));
            }
#pragma unroll
            for (int nq = 0; nq < 2; ++nq) {
                bf16x8 bfv[4];
#pragma unroll
                for (int nj = 0; nj < 4; ++nj) {
                    const int rn = wc*128 + nq*64 + nj*16 + fr;
                    bfv[nj] = *reinterpret_cast<const bf16x8*>(
                        ldsB + rn*128 + (((ko*4 + fq) ^ (rn & 7)) << 4));
                }
                __builtin_amdgcn_s_setprio(1);
#pragma unroll
                for (int mi = 0; mi < 4; ++mi)
#pragma unroll
                    for (int nj = 0; nj < 4; ++nj)
                        acc[mi][nq*4 + nj] = __builtin_amdgcn_mfma_f32_16x16x32_bf16(
                            af[mi], bfv[nj], acc[mi][nq*4 + nj], 0, 0, 0);
                __builtin_amdgcn_s_setprio(0);
            }
        }
    }

#pragma unroll
    for (int ni = 0; ni < 8; ++ni) {
        const int col = n0 + wc*128 + ni*16 + fr;
        const float bv = bias[col];
#pragma unroll
        for (int mi = 0; mi < 4; ++mi) {
            const int rowb = m0 + wr*64 + mi*16 + fq*4;
#pragma unroll
            for (int r = 0; r < 4; ++r)
                oo[(size_t)(rowb + r)*EMBD + col] = acc[mi][ni][r] + bv;
        }
    }
}

// ---------------- FALLBACK GEMM (round-0, known-good) -----------------------
__global__ __launch_bounds__(256, 2)
void embed_gemm_kernel(const float* __restrict__ x1, const float* __restrict__ xx2,
                       const float* __restrict__ Wm, const float* __restrict__ bias,
                       float* __restrict__ out) {
    __shared__ __align__(16) unsigned char As[128*64*2];
    __shared__ __align__(16) unsigned char Bs[128*64*2];

    const float* __restrict__ xin = blockIdx.y ? xx2 : x1;
    float* __restrict__ oo = out + (size_t)blockIdx.y * (size_t)O2_OFS;

    const int bx = blockIdx.x;
    const int swz = (bx & 7) * (1728/8) + (bx >> 3);
    const int mt = swz / 6;
    const int nt = swz - mt * 6;
    const int m0 = mt * 128;
    const int n0 = nt * 128;

    const int tid = threadIdx.x;

    int boffA[8], boffB[8], lofs[8];
#pragma unroll
    for (int it = 0; it < 8; ++it) {
        const int ci = tid + 256*it;
        const int row = ci >> 4, col4 = ci & 15;
        const int m = m0 + row;
        const int bb = m / NPATCH;
        const int p  = m - bb*NPATCH;
        const int py = p / FS, px = p - py*FS;
        boffA[it] = ((bb*3)*IMGW + py*16 + (col4 >> 2)) * IMGW + px*16 + (col4 & 3)*4;
        boffB[it] = (n0 + row)*KDIM + col4*4;
        lofs[it]  = (ci*8) ^ ((row & 7) << 4);
    }

    f32x4 acc[4][4];
#pragma unroll
    for (int i = 0; i < 4; ++i)
#pragma unroll
        for (int j = 0; j < 4; ++j) acc[i][j] = (f32x4){0.f, 0.f, 0.f, 0.f};

    f32x4 stA[8], stB[8];
#pragma unroll
    for (int it = 0; it < 8; ++it) {
        stA[it] = *reinterpret_cast<const f32x4*>(xin + boffA[it]);
        stB[it] = *reinterpret_cast<const f32x4*>(Wm + boffB[it]);
    }

    const int l  = tid & 63;
    const int wid = tid >> 6;
    const int wr = wid >> 1, wc = wid & 1;
    const int fr = l & 15, fq = l >> 4;
    const int xorv = (fr & 7) << 4;

    for (int kt = 0; kt < 12; ++kt) {
        __syncthreads();
#pragma unroll
        for (int it = 0; it < 8; ++it) {
            *reinterpret_cast<u16x4*>(As + lofs[it]) = cvt4_bf16(stA[it]);
            *reinterpret_cast<u16x4*>(Bs + lofs[it]) = cvt4_bf16(stB[it]);
        }
        if (kt + 1 < 12) {
            const int dA = ((kt+1) >> 2) * (IMGW*IMGW) + ((kt+1) & 3) * (4*IMGW);
            const int dB = (kt+1) * 64;
#pragma unroll
            for (int it = 0; it < 8; ++it) {
                stA[it] = *reinterpret_cast<const f32x4*>(xin + boffA[it] + dA);
                stB[it] = *reinterpret_cast<const f32x4*>(Wm + boffB[it] + dB);
            }
        }
        __syncthreads();
#pragma unroll
        for (int ko = 0; ko < 2; ++ko) {
            const int colb = ko*64 + fq*16;
            bf16x8 af[4], bf4[4];
#pragma unroll
            for (int i = 0; i < 4; ++i) {
                af[i]  = *reinterpret_cast<const bf16x8*>(As + (wr*64 + i*16 + fr)*128 + (colb ^ xorv));
                bf4[i] = *reinterpret_cast<const bf16x8*>(Bs + (wc*64 + i*16 + fr)*128 + (colb ^ xorv));
            }
#pragma unroll
            for (int mi = 0; mi < 4; ++mi)
#pragma unroll
                for (int ni = 0; ni < 4; ++ni)
                    acc[mi][ni] = __builtin_amdgcn_mfma_f32_16x16x32_bf16(
                        af[mi], bf4[ni], acc[mi][ni], 0, 0, 0);
        }
    }

#pragma unroll
    for (int ni = 0; ni < 4; ++ni) {
        const int col = n0 + wc*64 + ni*16 + fr;
        const float bv = bias[col];
#pragma unroll
        for (int mi = 0; mi < 4; ++mi) {
            const int rowb = m0 + wr*64 + mi*16 + fq*4;
#pragma unroll
            for (int r = 0; r < 4; ++r)
                oo[(size_t)(rowb + r)*EMBD + col] = acc[mi][ni][r] + bv;
        }
    }
}

// ---------------- masked per-channel stats (t split into gridDim.z) ---------
__global__ void stats_kernel(const float* __restrict__ o1, const float* __restrict__ o2,
                             float* __restrict__ ws) {
    const int b = blockIdx.y;
    const int c = blockIdx.x * 256 + threadIdx.x;
    const int t = blockIdx.z;

    float g[4];
#pragma unroll
    for (int i = 0; i < 4; ++i) g[i] = ws[(t ? WS_G2 : WS_G1) + b*4 + i];

    const float* f = t ? o2 : o1;
    int xlo = max(0, (int)g[0]);
    int xhi = min(FS, (int)g[2]);
    int ylo = max(0, (int)g[1]);
    int yhi = min(FS, (int)g[3]);
    float s = 0.f, ss = 0.f;
    for (int py = ylo; py < yhi; ++py)
        for (int px = xlo; px < xhi; ++px) {
            float v = f[(size_t)(b*NPATCH + py*FS + px)*EMBD + c];
            s += v; ss += v*v;
        }
    int nx = xhi - xlo; if (nx < 0) nx = 0;
    int ny = yhi - ylo; if (ny < 0) ny = 0;
    float n = (float)(nx*ny);
    float mean = s / fmaxf(n, 1.f);
    float var = (ss - 2.f*mean*s + n*mean*mean) / fmaxf(n - 1.f, 1.f);
    float sd = sqrtf(fmaxf(var, 0.f));
    ws[(t ? WS_MEAN2 : WS_MEAN1) + b*EMBD + c] = mean;
    ws[(t ? WS_STD2 : WS_STD1) + b*EMBD + c] = sd;
}

// ---------------- blend (r12 mega-grid version, proven fastest) -------------
__global__ void blend_kernel(float* __restrict__ o1, float* __restrict__ o2,
                             const float* __restrict__ ws) {
    const int b = blockIdx.y;
    const int p = blockIdx.x;
    const int py = p / FS, px = p - py*FS;
    const float pxf = (float)px, pyf = (float)py;

    const float sk1 = ws[WS_SK1 + b];
    const float sk2 = ws[WS_SK2 + b];
    const bool in1 = (pxf >= ws[WS_G1 + b*4+0]) && (pxf < ws[WS_G1 + b*4+2]) &&
                     (pyf >= ws[WS_G1 + b*4+1]) && (pyf < ws[WS_G1 + b*4+3]);
    const bool in2 = (pxf >= ws[WS_G2 + b*4+0]) && (pxf < ws[WS_G2 + b*4+2]) &&
                     (pyf >= ws[WS_G2 + b*4+1]) && (pyf < ws[WS_G2 + b*4+3]);
    const bool do1 = (sk1 == 0.f) && in2;
    const bool do2 = (sk2 == 0.f) && in1;
    if (!do1 && !do2) return;

    const int c = threadIdx.x * 4;
    const size_t base = (size_t)(b*NPATCH + p)*EMBD + c;
    const f32x4 f1 = *reinterpret_cast<const f32x4*>(o1 + base);
    const f32x4 f2 = *reinterpret_cast<const f32x4*>(o2 + base);
    const f32x4 m1 = *reinterpret_cast<const f32x4*>(ws + WS_MEAN1 + b*EMBD + c);
    const f32x4 s1 = *reinterpret_cast<const f32x4*>(ws + WS_STD1  + b*EMBD + c);
    const f32x4 m2 = *reinterpret_cast<const f32x4*>(ws + WS_MEAN2 + b*EMBD + c);
    const f32x4 s2 = *reinterpret_cast<const f32x4*>(ws + WS_STD2  + b*EMBD + c);

    if (do1) {
        f32x4 r;
#pragma unroll
        for (int j = 0; j < 4; ++j)
            r[j] = (f2[j] - m2[j]) / (s2[j] + EPSV) * (s1[j] + EPSV) + m1[j];
        *reinterpret_cast<f32x4*>(o1 + base) = r;
    }
    if (do2) {
        f32x4 r;
#pragma unroll
        for (int j = 0; j < 4; ++j)
            r[j] = (f1[j] - m1[j]) / (s1[j] + EPSV) * (s2[j] + EPSV) + m2[j];
        *reinterpret_cast<f32x4*>(o2 + base) = r;
    }
}

extern "C" void kernel_launch(void* const* d_in, const int* in_sizes, int n_in,
                              void* d_out, int out_size, void* d_ws, size_t ws_size,
                              hipStream_t stream) {
    const float* x    = (const float*)d_in[0];
    const float* x2   = (const float*)d_in[1];
    const float* gt1  = (const float*)d_in[2];
    const float* gt2  = (const float*)d_in[3];
    const float* Wm   = (const float*)d_in[4];
    const float* bias = (const float*)d_in[5];
    float* out = (float*)d_out;
    float* ws  = (float*)d_ws;

    float* o1 = out;
    float* o2 = out + O2_OFS;
    float* g1n = out + G1_OFS;
    float* g2n = out + G2_OFS;

    if (ws_size >= WS_NEED) {
        unsigned short* Wb = (unsigned short*)((char*)d_ws + WSB_W);
        init_kernel<<<289, 256, 0, stream>>>(gt1, gt2, g1n, g2n, ws, Wm, Wb);
        gemm_abf16_kernel<<<dim3(864, 2), 256, 0, stream>>>(x, x2, Wb, bias, out);
    } else {
        init_kernel<<<1, 256, 0, stream>>>(gt1, gt2, g1n, g2n, ws, Wm,
                                           (unsigned short*)((char*)d_ws + WSB_W));
        embed_gemm_kernel<<<dim3(1728, 2), 256, 0, stream>>>(x, x2, Wm, bias, out);
    }

    stats_kernel<<<dim3(3, NB, 2), 256, 0, stream>>>(o1, o2, ws);
    blend_kernel<<<dim3(NPATCH, NB), 192, 0, stream>>>(o1, o2, ws);
}